// Round 1
// baseline (1472.891 us; speedup 1.0000x reference)
//
#include <hip/hip_runtime.h>

// Problem constants (fixed by the reference).
#define N_STRUCT   1000
#define ATOMS      100
#define NSEG       (N_STRUCT * ATOMS)   // 100000 gradient segments
#define N_SAMP     100000               // values rows
#define N_GRAD     500000               // gradient rows
#define D_FEAT     128
#define GD         (3 * D_FEAT)         // 384 floats per gradient row
#define VAL_OUT    (N_STRUCT * D_FEAT)  // 128000 floats: offset of grad output

// ---------------- index-building kernels (tiny) ----------------

__global__ void zero_counts_kernel(int* __restrict__ counts) {
    int i = blockIdx.x * 256 + threadIdx.x;
    if (i < NSEG) counts[i] = 0;
}

__global__ void hist_kernel(const int* __restrict__ gs, const int* __restrict__ ga,
                            int* __restrict__ counts) {
    int i = blockIdx.x * 256 + threadIdx.x;
    if (i < N_GRAD) {
        int seg = gs[i] * ATOMS + ga[i];
        atomicAdd(&counts[seg], 1);
    }
}

// Single-block exclusive scan of counts -> offsets (and a second copy: cursors).
__global__ void scan_kernel(const int* __restrict__ counts, int* __restrict__ offsets,
                            int* __restrict__ cursors) {
    __shared__ int tile[1024];
    int carry = 0;
    for (int base = 0; base < NSEG; base += 1024) {
        int i = base + (int)threadIdx.x;
        int v = (i < NSEG) ? counts[i] : 0;
        tile[threadIdx.x] = v;
        __syncthreads();
        for (int d = 1; d < 1024; d <<= 1) {
            int t = (threadIdx.x >= (unsigned)d) ? tile[threadIdx.x - d] : 0;
            __syncthreads();
            tile[threadIdx.x] += t;
            __syncthreads();
        }
        int excl = tile[threadIdx.x] - v;   // exclusive within tile
        if (i < NSEG) { offsets[i] = carry + excl; cursors[i] = carry + excl; }
        carry += tile[1023];
        __syncthreads();                    // protect tile before next overwrite
    }
    if (threadIdx.x == 0) offsets[NSEG] = carry;
}

__global__ void scatter_kernel(const int* __restrict__ gs, const int* __restrict__ ga,
                               int* __restrict__ cursors, int* __restrict__ rowidx) {
    int i = blockIdx.x * 256 + threadIdx.x;
    if (i < N_GRAD) {
        int seg = gs[i] * ATOMS + ga[i];
        int pos = atomicAdd(&cursors[seg], 1);
        rowidx[pos] = i;
    }
}

// ---------------- fat kernels ----------------

// One block (384 threads) per gradient segment: gather & sum contributing rows.
// Each row is 1536 contiguous bytes -> fully coalesced reads; each output
// element written exactly once (zeros for empty segments -> no memset needed).
__global__ __launch_bounds__(GD) void grad_sum_kernel(
        const float* __restrict__ grad, const int* __restrict__ offsets,
        const int* __restrict__ rowidx, float* __restrict__ out) {
    int s  = blockIdx.x;
    int t  = threadIdx.x;           // 0..383
    int lo = offsets[s];
    int hi = offsets[s + 1];
    float acc = 0.0f;
    for (int j = lo; j < hi; ++j) {
        int r = rowidx[j];          // uniform across block -> broadcast
        acc += grad[(size_t)r * GD + t];
    }
    out[(size_t)s * GD + t] = acc;
}

// structure_ids is sorted: one block (128 threads) per structure, binary-search
// the segment boundaries, then sequential coalesced accumulate.
__global__ __launch_bounds__(D_FEAT) void values_sum_kernel(
        const float* __restrict__ values, const int* __restrict__ sid,
        float* __restrict__ out) {
    int s = blockIdx.x;
    int t = threadIdx.x;            // 0..127
    __shared__ int bounds[2];
    if (t < 2) {
        int target = s + t;         // lower_bound(s) and lower_bound(s+1)
        int lo = 0, hi = N_SAMP;
        while (lo < hi) {
            int mid = (lo + hi) >> 1;
            if (sid[mid] < target) lo = mid + 1; else hi = mid;
        }
        bounds[t] = lo;
    }
    __syncthreads();
    float acc = 0.0f;
    for (int i = bounds[0]; i < bounds[1]; ++i)
        acc += values[(size_t)i * D_FEAT + t];
    out[(size_t)s * D_FEAT + t] = acc;
}

// ---------------- launch ----------------

extern "C" void kernel_launch(void* const* d_in, const int* in_sizes, int n_in,
                              void* d_out, int out_size, void* d_ws, size_t ws_size,
                              hipStream_t stream) {
    const float* values = (const float*)d_in[0];
    const int*   sid    = (const int*)  d_in[1];
    const float* grad   = (const float*)d_in[2];
    const int*   gs     = (const int*)  d_in[3];
    const int*   ga     = (const int*)  d_in[4];
    float* out = (float*)d_out;

    // workspace layout (ints): counts[NSEG] | offsets[NSEG+1] | cursors[NSEG] | rowidx[N_GRAD]
    int* counts  = (int*)d_ws;
    int* offsets = counts + NSEG;
    int* cursors = offsets + NSEG + 1;
    int* rowidx  = cursors + NSEG;

    zero_counts_kernel<<<(NSEG + 255) / 256, 256, 0, stream>>>(counts);
    hist_kernel<<<(N_GRAD + 255) / 256, 256, 0, stream>>>(gs, ga, counts);
    scan_kernel<<<1, 1024, 0, stream>>>(counts, offsets, cursors);
    scatter_kernel<<<(N_GRAD + 255) / 256, 256, 0, stream>>>(gs, ga, cursors, rowidx);

    // Independent fat kernels.
    values_sum_kernel<<<N_STRUCT, D_FEAT, 0, stream>>>(values, sid, out);
    grad_sum_kernel<<<NSEG, GD, 0, stream>>>(grad, offsets, rowidx, out + VAL_OUT);
}